// Round 8
// baseline (135.201 us; speedup 1.0000x reference)
//
#include <hip/hip_runtime.h>
#include <hip/hip_bf16.h>
#include <math.h>

namespace {

constexpr int N    = 4096;   // rows (setup_inputs fixes this)
constexpr int D    = 128;    // embedding dim
constexpr int M    = 8;      // instances per class (consecutive)
constexpr int ROWS = 16;     // rows per rowset = 2 classes
constexpr int NRS  = N / ROWS;       // 256 rowsets
constexpr int NTA  = 512;            // panel_kernel threads (8 waves)
constexpr int NWA  = NTA / 64;
constexpr int NQ   = 4;              // column quarters
constexpr int CPW  = 8;              // chunks per wave in panel_kernel

// d_ws byte offsets
constexpr size_t XB_OFF    = 0;                          // bf16 X copy, 1 MB
constexpr size_t PANEL_OFF = (size_t)2 << 20;            // uint[2048][4096], 32 MB
constexpr size_t PART_OFF  = (size_t)34 << 20;           // f32 [NRS][NQ][16][2], 128 KB
constexpr size_t POS_OFF   = PART_OFF + ((size_t)128 << 10);  // f32 [NRS][16][8], 128 KB
constexpr size_t STATS_OFF = PART_OFF + ((size_t)256 << 10);  // f32 [N][4], 64 KB

using short8 = __attribute__((ext_vector_type(8))) short;
using f32x4  = __attribute__((ext_vector_type(4))) float;

__device__ __forceinline__ float bf2f(unsigned short u) {
    unsigned v = (unsigned)u << 16;
    return __builtin_bit_cast(float, v);
}
__device__ __forceinline__ unsigned short f2bf(float f) {
    unsigned u = __builtin_bit_cast(unsigned, f);
    u += 0x7FFFu + ((u >> 16) & 1u);          // RNE
    return (unsigned short)(u >> 16);
}
__device__ __forceinline__ float sp_fast(float z) {   // softplus, abs err ~1e-6
    return fmaxf(z, 0.f) + __logf(1.f + __expf(-fabsf(z)));
}
__device__ __forceinline__ unsigned pack_bf(float lo, float hi) {
    __hip_bfloat162 h = __float22bfloat162_rn(make_float2(lo, hi)); // x = lo bits
    unsigned u; __builtin_memcpy(&u, &h, 4); return u;
}
__device__ __forceinline__ float wsum64(float v) {
#pragma unroll
    for (int o = 32; o; o >>= 1) v += __shfl_down(v, o, 64);
    return v;
}

// fp32 -> bf16 copy of X; zero the output accumulator.
__global__ void cvt_kernel(const float* __restrict__ X,
                           unsigned short* __restrict__ Xb,
                           float* __restrict__ out)
{
    const int i = blockIdx.x * blockDim.x + threadIdx.x;  // one float4 each
    if (i == 0) out[0] = 0.f;
    const float4 v = reinterpret_cast<const float4*>(X)[i];
    ushort4 r;
    r.x = f2bf(v.x); r.y = f2bf(v.y); r.z = f2bf(v.z); r.w = f2bf(v.w);
    reinterpret_cast<ushort4*>(Xb)[i] = r;
}

// 1024 blocks (4/CU, 32 waves/CU). Block = (rowset rs, quarter q): computes
// sim[16 rows][1024 cols], stores row-pair-packed panel + partials + positives.
__global__ __launch_bounds__(NTA, 8)
void panel_kernel(const unsigned short* __restrict__ Xb,
                  unsigned* __restrict__ panelU,
                  float* __restrict__ part, float* __restrict__ pos)
{
    __shared__ float red[NWA * ROWS * 2];
    const int t    = threadIdx.x;
    const int lane = t & 63;
    const int w    = t >> 6;       // wave 0..7
    const int lr   = lane & 15;    // fragment col-lane
    const int lg   = lane >> 4;    // k-group / row-group
    const int rs   = blockIdx.x & (NRS - 1);
    const int q    = blockIdx.x >> 8;
    const int R0   = rs * ROWS;

    // A fragments (16 query rows): row lr, k = lg*8 + kk*32
    const unsigned short* qrow = Xb + (size_t)(R0 + lr) * D + lg * 8;
    const short8 afr0 = *reinterpret_cast<const short8*>(qrow);
    const short8 afr1 = *reinterpret_cast<const short8*>(qrow + 32);
    const short8 afr2 = *reinterpret_cast<const short8*>(qrow + 64);
    const short8 afr3 = *reinterpret_cast<const short8*>(qrow + 96);

    float sum4[4] = {0.f, 0.f, 0.f, 0.f};
    float sq4[4]  = {0.f, 0.f, 0.f, 0.f};

#pragma unroll
    for (int cc = 0; cc < CPW; ++cc) {
        const int chunk = q * 64 + cc * 8 + w;    // covers [0,256) over (q,cc,w)
        const int j = chunk * 16;
        const unsigned short* brow = Xb + (size_t)(j + lr) * D + lg * 8;
        const short8 b0 = *reinterpret_cast<const short8*>(brow);
        const short8 b1 = *reinterpret_cast<const short8*>(brow + 32);
        const short8 b2 = *reinterpret_cast<const short8*>(brow + 64);
        const short8 b3 = *reinterpret_cast<const short8*>(brow + 96);

        f32x4 acc = {0.f, 0.f, 0.f, 0.f};
        acc = __builtin_amdgcn_mfma_f32_16x16x32_bf16(afr0, b0, acc, 0, 0, 0);
        acc = __builtin_amdgcn_mfma_f32_16x16x32_bf16(afr1, b1, acc, 0, 0, 0);
        acc = __builtin_amdgcn_mfma_f32_16x16x32_bf16(afr2, b2, acc, 0, 0, 0);
        acc = __builtin_amdgcn_mfma_f32_16x16x32_bf16(afr3, b3, acc, 0, 0, 0);

        // D layout: local row = lg*4+i, col = j+lr
        const bool cls = (chunk == rs) && ((lr >> 3) == (lg >> 1));
        if (!cls) {
#pragma unroll
            for (int i = 0; i < 4; ++i) {
                const float v = acc[i];
                sum4[i] += v; sq4[i] += v * v;
            }
        } else {
#pragma unroll
            for (int i = 0; i < 4; ++i)          // fp32 positives
                pos[rs * 128 + (lg * 4 + i) * 8 + (lr & 7)] = acc[i];
        }
        // row-pair packed panel: word = (row even | row odd << 16)
        const unsigned pk0 = pack_bf(acc[0], acc[1]);   // rows R0+lg*4+0,1
        const unsigned pk1 = pack_bf(acc[2], acc[3]);   // rows R0+lg*4+2,3
        const int rp = rs * 8 + lg * 2;
        panelU[(size_t)rp * N + j + lr]       = pk0;
        panelU[(size_t)(rp + 1) * N + j + lr] = pk1;
    }

    // 16-lane reduce within each row-group, fold 8 waves, publish quarter slot
#pragma unroll
    for (int i = 0; i < 4; ++i) {
        float s = sum4[i], qq = sq4[i];
#pragma unroll
        for (int off = 8; off; off >>= 1) {
            s  += __shfl_down(s, off, 16);
            qq += __shfl_down(qq, off, 16);
        }
        if (lr == 0) {
            red[(w * ROWS + lg * 4 + i) * 2]     = s;
            red[(w * ROWS + lg * 4 + i) * 2 + 1] = qq;
        }
    }
    __syncthreads();
    if (t < ROWS) {
        float s = 0.f, qq = 0.f;
        for (int ww = 0; ww < NWA; ++ww) {
            s  += red[(ww * ROWS + t) * 2];
            qq += red[(ww * ROWS + t) * 2 + 1];
        }
        float* slot = &part[((rs * NQ + q) * ROWS + t) * 2];
        slot[0] = s; slot[1] = qq;
    }
}

// one thread per row: fold quarter partials + positives -> inter/thr/pos_loss
__global__ void stats_kernel(const float* __restrict__ part,
                             const float* __restrict__ pos,
                             float* __restrict__ stats)
{
    const int r = blockIdx.x * blockDim.x + threadIdx.x;   // 0..4095
    const int rs = r >> 4, rl = r & 15;
    float tot = 0.f, totsq = 0.f;
    for (int q = 0; q < NQ; ++q) {
        const float* slot = &part[((rs * NQ + q) * ROWS + rl) * 2];
        tot += slot[0]; totsq += slot[1];
    }
    float psum = 0.f, psq = 0.f, pmin = 1e30f;
    float pv[M];
#pragma unroll
    for (int p = 0; p < M; ++p) pv[p] = pos[rs * 128 + rl * 8 + p];
#pragma unroll
    for (int p = 0; p < M; ++p) {
        if (p == (rl & 7)) continue;
        psum += pv[p]; psq += pv[p] * pv[p]; pmin = fminf(pmin, pv[p]);
    }
    const float kinv  = 1.f / (float)(M - 1);
    const float pmean = psum * kinv;
    const float pstd  = sqrtf(fmaxf(psq * kinv - pmean * pmean, 0.f));
    const float ninv  = 1.f / (float)(N - M);
    const float nmean = tot * ninv;
    const float nstd  = sqrtf(fmaxf(totsq * ninv - nmean * nmean, 0.f));
    float inter = (nstd * pmean + pstd * nmean) / (pstd + nstd);
    inter = 0.8f * inter + 0.1f;

    float pl = 0.f;
#pragma unroll
    for (int p = 0; p < M; ++p) {
        if (p == (rl & 7)) continue;
        pl += sp_fast(-10.f * (pv[p] - inter));
    }
    pl *= 0.2f * kinv;

    stats[r * 4 + 0] = inter;
    stats[r * 4 + 1] = pmin - 0.05f;
    stats[r * 4 + 2] = pl;
}

// 2048 blocks (8/CU), block = one row-pair: stream 16KB of packed panel,
// kept-negative softplus for both rows, one atomicAdd.
__global__ __launch_bounds__(256, 8)
void neg_kernel(const unsigned* __restrict__ panelU,
                const float* __restrict__ stats, float* __restrict__ out)
{
    __shared__ float red[4][4];
    const int t  = threadIdx.x;
    const int wv = t >> 6;
    const int l  = t & 63;
    const int pair = blockIdx.x;           // rows 2*pair, 2*pair+1
    const int r0 = pair * 2;

    const float i0 = stats[r0 * 4 + 0], th0 = stats[r0 * 4 + 1], pl0 = stats[r0 * 4 + 2];
    const float i1 = stats[(r0 + 1) * 4 + 0], th1 = stats[(r0 + 1) * 4 + 1],
                pl1 = stats[(r0 + 1) * 4 + 2];
    const int cls0 = (r0 >> 3) << 3;       // class block cols (same for the pair)
    const unsigned* base = panelU + (size_t)pair * N;

    float nl0 = 0.f, c0 = 0.f, nl1 = 0.f, c1 = 0.f;
#pragma unroll
    for (int it = 0; it < 4; ++it) {
        const int col0 = wv * 1024 + it * 256 + l * 4;
        const uint4 u = *reinterpret_cast<const uint4*>(base + col0);
#pragma unroll
        for (int e = 0; e < 4; ++e) {
            const int col = col0 + e;
            if ((unsigned)(col - cls0) < 8u) continue;   // skip class block
            const unsigned pw = (&u.x)[e];
            const float vlo = bf2f((unsigned short)pw);          // even row
            const float vhi = bf2f((unsigned short)(pw >> 16));  // odd row
            if (vlo > th0) { c0 += 1.f; nl0 += sp_fast(40.f * (vlo - i0)); }
            if (vhi > th1) { c1 += 1.f; nl1 += sp_fast(40.f * (vhi - i1)); }
        }
    }

    nl0 = wsum64(nl0); c0 = wsum64(c0);
    nl1 = wsum64(nl1); c1 = wsum64(c1);
    if (l == 0) { red[wv][0] = nl0; red[wv][1] = c0; red[wv][2] = nl1; red[wv][3] = c1; }
    __syncthreads();
    if (t == 0) {
        float a0 = 0.f, b0 = 0.f, a1 = 0.f, b1 = 0.f;
        for (int v = 0; v < 4; ++v) {
            a0 += red[v][0]; b0 += red[v][1]; a1 += red[v][2]; b1 += red[v][3];
        }
        const float loss = pl0 + 0.05f * a0 / fmaxf(b0, 1.f)
                         + pl1 + 0.05f * a1 / fmaxf(b1, 1.f);
        atomicAdd(out, loss * (1.f / (float)N));
    }
}

} // namespace

extern "C" void kernel_launch(void* const* d_in, const int* in_sizes, int n_in,
                              void* d_out, int out_size, void* d_ws, size_t ws_size,
                              hipStream_t stream)
{
    const float* X = (const float*)d_in[0];          // [N][D] fp32 normalized
    float* out = (float*)d_out;
    char* ws = (char*)d_ws;
    unsigned short* Xb = (unsigned short*)(ws + XB_OFF);
    unsigned* panelU   = (unsigned*)(ws + PANEL_OFF);
    float* part        = (float*)(ws + PART_OFF);
    float* pos         = (float*)(ws + POS_OFF);
    float* stats       = (float*)(ws + STATS_OFF);

    cvt_kernel<<<dim3(N * D / 4 / 256), dim3(256), 0, stream>>>(X, Xb, out);
    panel_kernel<<<dim3(NRS * NQ), dim3(NTA), 0, stream>>>(Xb, panelU, part, pos);
    stats_kernel<<<dim3(N / 256), dim3(256), 0, stream>>>(part, pos, stats);
    neg_kernel<<<dim3(N / 2), dim3(256), 0, stream>>>(panelU, stats, out);
}

// Round 9
// 133.455 us; speedup vs baseline: 1.0131x; 1.0131x over previous
//
#include <hip/hip_runtime.h>
#include <hip/hip_bf16.h>
#include <math.h>

namespace {

constexpr int N    = 4096;   // rows (setup_inputs fixes this)
constexpr int D    = 128;    // embedding dim
constexpr int M    = 8;      // instances per class (consecutive)
constexpr int ROWS = 16;     // rows per rowset = 2 classes
constexpr int NRS  = N / ROWS;       // 256 rowsets
constexpr int NT   = 512;            // big-kernel threads (8 waves)
constexpr int NWA  = NT / 64;
constexpr int NQ   = 4;              // column quarters
constexpr int CPW  = 8;              // 16-col chunks per wave

// d_ws byte offsets (total < 1.5 MB; no panel!)
constexpr size_t XB_OFF    = 0;                              // bf16 X, 1 MB
constexpr size_t PART_OFF  = (size_t)1 << 20;                // f32 [NRS][NQ][16][2]
constexpr size_t POS_OFF   = PART_OFF  + ((size_t)128 << 10);// f32 [NRS][16][8]
constexpr size_t STATS_OFF = POS_OFF   + ((size_t)128 << 10);// f32 [N][4]
constexpr size_t NEGP_OFF  = STATS_OFF + ((size_t)64  << 10);// f32 [NRS][NQ][16][2]

using short8 = __attribute__((ext_vector_type(8))) short;
using f32x4  = __attribute__((ext_vector_type(4))) float;

__device__ __forceinline__ unsigned short f2bf(float f) {
    unsigned u = __builtin_bit_cast(unsigned, f);
    u += 0x7FFFu + ((u >> 16) & 1u);          // RNE
    return (unsigned short)(u >> 16);
}
__device__ __forceinline__ float sp_fast(float z) {   // softplus, abs err ~1e-6
    return fmaxf(z, 0.f) + __logf(1.f + __expf(-fabsf(z)));
}
__device__ __forceinline__ float wsum64(float v) {
#pragma unroll
    for (int o = 32; o; o >>= 1) v += __shfl_down(v, o, 64);
    return v;
}

// fp32 -> bf16 copy of X; zero the output accumulator.
__global__ void cvt_kernel(const float* __restrict__ X,
                           unsigned short* __restrict__ Xb,
                           float* __restrict__ out)
{
    const int i = blockIdx.x * blockDim.x + threadIdx.x;  // one float4 each
    if (i == 0) out[0] = 0.f;
    const float4 v = reinterpret_cast<const float4*>(X)[i];
    ushort4 r;
    r.x = f2bf(v.x); r.y = f2bf(v.y); r.z = f2bf(v.z); r.w = f2bf(v.w);
    reinterpret_cast<ushort4*>(Xb)[i] = r;
}

// 1024 blocks (4/CU, 32 waves/CU). Block (rowset rs, quarter q): streams
// sim[16][1024] via MFMA, accumulating Sigma/Sigma^2 only. No panel storage.
__global__ __launch_bounds__(NT, 8)
void sum_kernel(const unsigned short* __restrict__ Xb,
                float* __restrict__ part, float* __restrict__ pos)
{
    __shared__ float red[NWA * ROWS * 2];
    const int t    = threadIdx.x;
    const int lane = t & 63;
    const int w    = t >> 6;
    const int lr   = lane & 15;    // fragment col-lane
    const int lg   = lane >> 4;    // k-group / row-group
    const int rs   = blockIdx.x & (NRS - 1);
    const int q    = blockIdx.x >> 8;
    const int R0   = rs * ROWS;

    const unsigned short* qrow = Xb + (size_t)(R0 + lr) * D + lg * 8;
    const short8 afr0 = *reinterpret_cast<const short8*>(qrow);
    const short8 afr1 = *reinterpret_cast<const short8*>(qrow + 32);
    const short8 afr2 = *reinterpret_cast<const short8*>(qrow + 64);
    const short8 afr3 = *reinterpret_cast<const short8*>(qrow + 96);

    float sum4[4] = {0.f, 0.f, 0.f, 0.f};
    float sq4[4]  = {0.f, 0.f, 0.f, 0.f};

#pragma unroll
    for (int cc = 0; cc < CPW; ++cc) {
        const int chunk = q * 64 + cc * 8 + w;
        const int j = chunk * 16;
        const unsigned short* brow = Xb + (size_t)(j + lr) * D + lg * 8;
        const short8 b0 = *reinterpret_cast<const short8*>(brow);
        const short8 b1 = *reinterpret_cast<const short8*>(brow + 32);
        const short8 b2 = *reinterpret_cast<const short8*>(brow + 64);
        const short8 b3 = *reinterpret_cast<const short8*>(brow + 96);

        f32x4 acc = {0.f, 0.f, 0.f, 0.f};
        acc = __builtin_amdgcn_mfma_f32_16x16x32_bf16(afr0, b0, acc, 0, 0, 0);
        acc = __builtin_amdgcn_mfma_f32_16x16x32_bf16(afr1, b1, acc, 0, 0, 0);
        acc = __builtin_amdgcn_mfma_f32_16x16x32_bf16(afr2, b2, acc, 0, 0, 0);
        acc = __builtin_amdgcn_mfma_f32_16x16x32_bf16(afr3, b3, acc, 0, 0, 0);

        // D layout: local row = lg*4+i, col = j+lr
        const bool cls = (chunk == rs) && ((lr >> 3) == (lg >> 1));
        if (!cls) {
#pragma unroll
            for (int i = 0; i < 4; ++i) {
                const float v = acc[i];
                sum4[i] += v; sq4[i] += v * v;
            }
        } else {
#pragma unroll
            for (int i = 0; i < 4; ++i)          // fp32 positives
                pos[rs * 128 + (lg * 4 + i) * 8 + (lr & 7)] = acc[i];
        }
    }

#pragma unroll
    for (int i = 0; i < 4; ++i) {
        float s = sum4[i], qq = sq4[i];
#pragma unroll
        for (int off = 8; off; off >>= 1) {
            s  += __shfl_down(s, off, 16);
            qq += __shfl_down(qq, off, 16);
        }
        if (lr == 0) {
            red[(w * ROWS + lg * 4 + i) * 2]     = s;
            red[(w * ROWS + lg * 4 + i) * 2 + 1] = qq;
        }
    }
    __syncthreads();
    if (t < ROWS) {
        float s = 0.f, qq = 0.f;
        for (int ww = 0; ww < NWA; ++ww) {
            s  += red[(ww * ROWS + t) * 2];
            qq += red[(ww * ROWS + t) * 2 + 1];
        }
        float* slot = &part[((rs * NQ + q) * ROWS + t) * 2];
        slot[0] = s; slot[1] = qq;
    }
}

// one thread per row: fold quarter partials + positives -> inter/thr/pos_loss
__global__ void stats_kernel(const float* __restrict__ part,
                             const float* __restrict__ pos,
                             float* __restrict__ stats)
{
    const int r = blockIdx.x * blockDim.x + threadIdx.x;   // 0..4095
    const int rs = r >> 4, rl = r & 15;
    float tot = 0.f, totsq = 0.f;
    for (int q = 0; q < NQ; ++q) {
        const float* slot = &part[((rs * NQ + q) * ROWS + rl) * 2];
        tot += slot[0]; totsq += slot[1];
    }
    float psum = 0.f, psq = 0.f, pmin = 1e30f;
    float pv[M];
#pragma unroll
    for (int p = 0; p < M; ++p) pv[p] = pos[rs * 128 + rl * 8 + p];
#pragma unroll
    for (int p = 0; p < M; ++p) {
        if (p == (rl & 7)) continue;
        psum += pv[p]; psq += pv[p] * pv[p]; pmin = fminf(pmin, pv[p]);
    }
    const float kinv  = 1.f / (float)(M - 1);
    const float pmean = psum * kinv;
    const float pstd  = sqrtf(fmaxf(psq * kinv - pmean * pmean, 0.f));
    const float ninv  = 1.f / (float)(N - M);
    const float nmean = tot * ninv;
    const float nstd  = sqrtf(fmaxf(totsq * ninv - nmean * nmean, 0.f));
    float inter = (nstd * pmean + pstd * nmean) / (pstd + nstd);
    inter = 0.8f * inter + 0.1f;

    float pl = 0.f;
#pragma unroll
    for (int p = 0; p < M; ++p) {
        if (p == (rl & 7)) continue;
        pl += sp_fast(-10.f * (pv[p] - inter));
    }
    pl *= 0.2f * kinv;

    stats[r * 4 + 0] = inter;
    stats[r * 4 + 1] = pmin - 0.05f;
    stats[r * 4 + 2] = pl;
}

// Same streaming structure as sum_kernel; recomputes sim and applies the
// kept-negative softplus directly on fp32 accumulators.
__global__ __launch_bounds__(NT, 8)
void negstream_kernel(const unsigned short* __restrict__ Xb,
                      const float* __restrict__ stats,
                      float* __restrict__ negp)
{
    __shared__ float red[NWA * ROWS * 2];
    const int t    = threadIdx.x;
    const int lane = t & 63;
    const int w    = t >> 6;
    const int lr   = lane & 15;
    const int lg   = lane >> 4;
    const int rs   = blockIdx.x & (NRS - 1);
    const int q    = blockIdx.x >> 8;
    const int R0   = rs * ROWS;

    const unsigned short* qrow = Xb + (size_t)(R0 + lr) * D + lg * 8;
    const short8 afr0 = *reinterpret_cast<const short8*>(qrow);
    const short8 afr1 = *reinterpret_cast<const short8*>(qrow + 32);
    const short8 afr2 = *reinterpret_cast<const short8*>(qrow + 64);
    const short8 afr3 = *reinterpret_cast<const short8*>(qrow + 96);

    float itr4[4], thr4[4];
#pragma unroll
    for (int i = 0; i < 4; ++i) {
        itr4[i] = stats[(R0 + lg * 4 + i) * 4 + 0];
        thr4[i] = stats[(R0 + lg * 4 + i) * 4 + 1];
    }
    float nls[4] = {0.f, 0.f, 0.f, 0.f};
    float cnt[4] = {0.f, 0.f, 0.f, 0.f};

#pragma unroll
    for (int cc = 0; cc < CPW; ++cc) {
        const int chunk = q * 64 + cc * 8 + w;
        const int j = chunk * 16;
        const unsigned short* brow = Xb + (size_t)(j + lr) * D + lg * 8;
        const short8 b0 = *reinterpret_cast<const short8*>(brow);
        const short8 b1 = *reinterpret_cast<const short8*>(brow + 32);
        const short8 b2 = *reinterpret_cast<const short8*>(brow + 64);
        const short8 b3 = *reinterpret_cast<const short8*>(brow + 96);

        f32x4 acc = {0.f, 0.f, 0.f, 0.f};
        acc = __builtin_amdgcn_mfma_f32_16x16x32_bf16(afr0, b0, acc, 0, 0, 0);
        acc = __builtin_amdgcn_mfma_f32_16x16x32_bf16(afr1, b1, acc, 0, 0, 0);
        acc = __builtin_amdgcn_mfma_f32_16x16x32_bf16(afr2, b2, acc, 0, 0, 0);
        acc = __builtin_amdgcn_mfma_f32_16x16x32_bf16(afr3, b3, acc, 0, 0, 0);

        const bool cls = (chunk == rs) && ((lr >> 3) == (lg >> 1));
#pragma unroll
        for (int i = 0; i < 4; ++i) {
            const float v = acc[i];
            if (!cls && v > thr4[i]) {
                cnt[i] += 1.f;
                nls[i] += sp_fast(40.f * (v - itr4[i]));
            }
        }
    }

#pragma unroll
    for (int i = 0; i < 4; ++i) {
        float s = nls[i], c = cnt[i];
#pragma unroll
        for (int off = 8; off; off >>= 1) {
            s += __shfl_down(s, off, 16);
            c += __shfl_down(c, off, 16);
        }
        if (lr == 0) {
            red[(w * ROWS + lg * 4 + i) * 2]     = s;
            red[(w * ROWS + lg * 4 + i) * 2 + 1] = c;
        }
    }
    __syncthreads();
    if (t < ROWS) {
        float a = 0.f, b = 0.f;
        for (int ww = 0; ww < NWA; ++ww) {
            a += red[(ww * ROWS + t) * 2];
            b += red[(ww * ROWS + t) * 2 + 1];
        }
        float* slot = &negp[((rs * NQ + q) * ROWS + t) * 2];
        slot[0] = a; slot[1] = b;
    }
}

// fold per-quarter neg partials, add pos_loss, reduce to the scalar output
__global__ void final_kernel(const float* __restrict__ stats,
                             const float* __restrict__ negp,
                             float* __restrict__ out)
{
    const int r = blockIdx.x * blockDim.x + threadIdx.x;   // 0..4095
    const int rs = r >> 4, rl = r & 15;
    float a = 0.f, b = 0.f;
    for (int q = 0; q < NQ; ++q) {
        const float* slot = &negp[((rs * NQ + q) * ROWS + rl) * 2];
        a += slot[0]; b += slot[1];
    }
    float loss = stats[r * 4 + 2] + 0.05f * a / fmaxf(b, 1.f);
    loss = wsum64(loss);
    if ((threadIdx.x & 63) == 0) atomicAdd(out, loss * (1.f / (float)N));
}

} // namespace

extern "C" void kernel_launch(void* const* d_in, const int* in_sizes, int n_in,
                              void* d_out, int out_size, void* d_ws, size_t ws_size,
                              hipStream_t stream)
{
    const float* X = (const float*)d_in[0];          // [N][D] fp32 normalized
    float* out = (float*)d_out;
    char* ws = (char*)d_ws;
    unsigned short* Xb = (unsigned short*)(ws + XB_OFF);
    float* part  = (float*)(ws + PART_OFF);
    float* pos   = (float*)(ws + POS_OFF);
    float* stats = (float*)(ws + STATS_OFF);
    float* negp  = (float*)(ws + NEGP_OFF);

    cvt_kernel<<<dim3(N * D / 4 / 256), dim3(256), 0, stream>>>(X, Xb, out);
    sum_kernel<<<dim3(NRS * NQ), dim3(NT), 0, stream>>>(Xb, part, pos);
    stats_kernel<<<dim3(N / 256), dim3(256), 0, stream>>>(part, pos, stats);
    negstream_kernel<<<dim3(NRS * NQ), dim3(NT), 0, stream>>>(Xb, stats, negp);
    final_kernel<<<dim3(N / 256), dim3(256), 0, stream>>>(stats, negp, out);
}